// Round 22
// baseline (167.490 us; speedup 1.0000x reference)
//
#include <hip/hip_runtime.h>
#include <hip/hip_bf16.h>
#include <math.h>

#define NRL 4
#define LL 4096
#define NFFT 4104
#define LP 4224
#define NB 64
#define WD 64
#define BST (LP*WD*2)        // 540672 bytes per batch plane (tiled layout)
#define LCH 33               // l-chunks of 128
#define PCH 33               // partial chunks
#define NLB 264              // l-tiles of 16 (LP/16)
#define PI2 6.28318530717958647692f

typedef __attribute__((ext_vector_type(8))) short short8;
typedef __attribute__((ext_vector_type(4))) short short4v;
typedef __attribute__((ext_vector_type(4))) float f32x4;

__device__ inline unsigned short f2bf(float f){
  unsigned int u = __float_as_uint(f);
  return (unsigned short)((u + 0x7FFFu + ((u>>16)&1u)) >> 16);
}
__device__ inline unsigned pk_bf(float lo, float hi){
  unsigned r;
  asm("v_cvt_pk_bf16_f32 %0, %1, %2" : "=v"(r) : "v"(lo), "v"(hi));
  return r;
}
// tanh-form gelu: |err vs erf-gelu| <= ~5e-4
__device__ inline float gelu_f(float v){
  float v2 = v*v;
  float z = v * fmaf(0.07135481627f, v2, 1.5957691216f);
  float e = __expf(-z);
  return v * __builtin_amdgcn_rcpf(1.0f + e);
}

// x-plane tiled layout: per b, [lblk 264][cks 2][lane 64][e 8] bf16 (1KB tiles)

// ---- prologue: tf (1056) | tif tiled (1056) | conv-w frags hi (64) |
//      transposed spectral weights twr (2048) | twi (2048)
__global__ void k_tables(const float* __restrict__ cw,
                         const float* __restrict__ swr, const float* __restrict__ swi,
                         unsigned short* __restrict__ tf,
                         unsigned short* __restrict__ tif,
                         unsigned short* __restrict__ whi,
                         float* __restrict__ twr, float* __restrict__ twi){
  int bid = blockIdx.x;
  if (bid < 1056){
    int idx = bid*256 + threadIdx.x;          // 270336
    int e = idx & 7; int t = idx >> 3;
    int lane = t & 63; int t2 = t >> 6;
    int js = t2 & 3; int ks = t2 >> 2;
    int l = ks*32 + 8*(lane>>4) + e;
    int j = js*16 + (lane & 15);
    int m = j >> 1;
    float v = 0.f;
    if (l < NFFT){
      int r = (m*l) % NFFT;
      float ang = PI2 * ((float)r / (float)NFFT);
      v = (j & 1) ? -__sinf(ang) : __cosf(ang);
    }
    tf[idx] = f2bf(v);
  } else if (bid < 2112){
    int idx = (bid-1056)*256 + threadIdx.x;   // 270336
    int e = idx & 7; int t = idx >> 3;
    int lane = t & 63; int u = t >> 6;
    int lblk = u % NLB; int ks = u / NLB;
    int j2 = ks*32 + 8*(lane>>4) + e;
    int l = lblk*16 + (lane & 15);
    int m = j2 >> 1;
    float v = 0.f;
    if (l < NFFT){
      int r = (m*l) % NFFT;
      float ang = PI2 * ((float)r / (float)NFFT);
      float inv = 1.0f/(float)NFFT;
      v = (j2 & 1) ? (-2.f*inv*__sinf(ang)) : ((m==0?inv:2.f*inv)*__cosf(ang));
    }
    tif[idx] = f2bf(v);
  } else if (bid < 2176){
    int idx = (bid-2112)*256 + threadIdx.x;   // 16384
    int e = idx & 7; int lane = (idx>>3)&63; int os = (idx>>9)&3;
    int ks2 = (idx>>11)&1; int ly = idx>>12;
    int k = ks2*32 + 8*(lane>>4) + e;
    int o = os*16 + (lane&15);
    whi[idx] = f2bf(cw[((size_t)(ly*64 + o))*64 + k]);
  } else if (bid < 4224){
    int idx = (bid-2176)*256 + threadIdx.x;   // 524288: [ly][m][i][o]
    int o = idx & 63, i = (idx>>6)&63, m = (idx>>12)&31, ly = idx>>17;
    twr[idx] = swr[(((size_t)(ly*64 + i)*64 + o))*32 + m];
  } else {
    int idx = (bid-4224)*256 + threadIdx.x;   // 524288
    int o = idx & 63, i = (idx>>6)&63, m = (idx>>12)&31, ly = idx>>17;
    twi[idx] = swi[(((size_t)(ly*64 + i)*64 + o))*32 + m];
  }
}

// LDS transpose tile: ldt[os 4][l 128][c 16] u16 (row = 32B).
// Wave-private subtile: no __syncthreads needed (lgkmcnt wait only).
#define LDT_BYTES 16384

__device__ inline void dft_partial(const unsigned short* ldt_base, int os, int q, int lr,
                                   const unsigned short* __restrict__ tf, int chunk,
                                   f32x4 a2[4]){
  unsigned ab = (unsigned)(size_t)ldt_base + (unsigned)(os*4096 + q*256 + lr*2);
  short4v t0,t1,t2,t3,t4,t5,t6,t7;
  asm volatile("s_waitcnt lgkmcnt(0)" ::: "memory");   // own ds_writes complete
  asm volatile("ds_read_b64_tr_b16 %0, %1 offset:0"    : "=v"(t0) : "v"(ab) : "memory");
  asm volatile("ds_read_b64_tr_b16 %0, %1 offset:128"  : "=v"(t1) : "v"(ab) : "memory");
  asm volatile("ds_read_b64_tr_b16 %0, %1 offset:1024" : "=v"(t2) : "v"(ab) : "memory");
  asm volatile("ds_read_b64_tr_b16 %0, %1 offset:1152" : "=v"(t3) : "v"(ab) : "memory");
  asm volatile("ds_read_b64_tr_b16 %0, %1 offset:2048" : "=v"(t4) : "v"(ab) : "memory");
  asm volatile("ds_read_b64_tr_b16 %0, %1 offset:2176" : "=v"(t5) : "v"(ab) : "memory");
  asm volatile("ds_read_b64_tr_b16 %0, %1 offset:3072" : "=v"(t6) : "v"(ab) : "memory");
  asm volatile("ds_read_b64_tr_b16 %0, %1 offset:3200" : "=v"(t7) : "v"(ab) : "memory");
  asm volatile("s_waitcnt lgkmcnt(0)" ::: "memory");
  __builtin_amdgcn_sched_barrier(0);
  short8 av0 = __builtin_shufflevector(t0, t1, 0,1,2,3,4,5,6,7);
  short8 av1 = __builtin_shufflevector(t2, t3, 0,1,2,3,4,5,6,7);
  short8 av2 = __builtin_shufflevector(t4, t5, 0,1,2,3,4,5,6,7);
  short8 av3 = __builtin_shufflevector(t6, t7, 0,1,2,3,4,5,6,7);
  int lane = q*16 + lr;
  #pragma unroll
  for (int js=0;js<4;js++){
    short8 bv0 = *(const short8*)(tf + ((size_t)(((chunk*4 + 0)*4 + js)*64 + lane))*8);
    a2[js] = __builtin_amdgcn_mfma_f32_16x16x32_bf16(av0, bv0, a2[js], 0,0,0);
    short8 bv1 = *(const short8*)(tf + ((size_t)(((chunk*4 + 1)*4 + js)*64 + lane))*8);
    a2[js] = __builtin_amdgcn_mfma_f32_16x16x32_bf16(av1, bv1, a2[js], 0,0,0);
    short8 bv2 = *(const short8*)(tf + ((size_t)(((chunk*4 + 2)*4 + js)*64 + lane))*8);
    a2[js] = __builtin_amdgcn_mfma_f32_16x16x32_bf16(av2, bv2, a2[js], 0,0,0);
    short8 bv3 = *(const short8*)(tf + ((size_t)(((chunk*4 + 3)*4 + js)*64 + lane))*8);
    a2[js] = __builtin_amdgcn_mfma_f32_16x16x32_bf16(av3, bv3, a2[js], 0,0,0);
  }
}

// ---- fused lift: lifted x -> tiled plane + LDS transpose -> partial DFT chunk
__global__ __launch_bounds__(256) void k_lift2(const float* __restrict__ x,
    const float* __restrict__ lw, const float* __restrict__ lb,
    const unsigned short* __restrict__ tf,
    unsigned short* __restrict__ xh, unsigned* __restrict__ pout){
  __shared__ __align__(16) unsigned short ldt[LDT_BYTES/2];
  __shared__ float xs[128];
  int l0 = blockIdx.x*128; int b = blockIdx.y;
  int tid = threadIdx.x;
  int os = tid >> 6, lane = tid & 63, q = lane >> 4, lr = lane & 15;
  if (tid < 32){
    float4 v = make_float4(0.f,0.f,0.f,0.f);
    int l = l0 + tid*4;
    if (l < LL) v = *(const float4*)(x + (size_t)b*LL + l);
    *(float4*)(xs + tid*4) = v;
  }
  __syncthreads();        // xs is cross-wave shared: keep this barrier
  float w0[4], w1[4], bb[4];
  #pragma unroll
  for (int r=0;r<4;r++){
    int c = os*16 + 4*q + r;
    w0[r] = lw[2*c]; w1[r] = lw[2*c+1]; bb[r] = lb[c];
  }
  char* nb = (char*)xh + (size_t)b*BST;
  int cks = os >> 1;
  int qp  = (os & 1)*2 + (q >> 1);
  int e0  = (q & 1)*4;
  char* ldb = (char*)ldt + os*4096 + q*8;
  #pragma unroll
  for (int ls=0;ls<8;ls++){
    int lrow = ls*16 + lr; int l = l0 + lrow;
    float g = (float)l * (1.0f/4095.0f);
    float v0 = (l < LL) ? fmaf(w0[0], xs[lrow], fmaf(w1[0], g, bb[0])) : 0.f;
    float v1 = (l < LL) ? fmaf(w0[1], xs[lrow], fmaf(w1[1], g, bb[1])) : 0.f;
    float v2 = (l < LL) ? fmaf(w0[2], xs[lrow], fmaf(w1[2], g, bb[2])) : 0.f;
    float v3 = (l < LL) ? fmaf(w0[3], xs[lrow], fmaf(w1[3], g, bb[3])) : 0.f;
    unsigned h0 = pk_bf(v0, v1), h1 = pk_bf(v2, v3);
    int lblk = blockIdx.x*8 + ls;
    *(uint2*)(nb + ((size_t)(lblk*2 + cks))*1024 + (qp*16 + lr)*16 + e0*2) = make_uint2(h0,h1);
    *(uint2*)(ldb + lrow*32) = make_uint2(h0,h1);
  }
  // no barrier: ldt subtile is wave-private (dft_partial waits lgkmcnt)
  f32x4 a2[4];
  #pragma unroll
  for (int js=0;js<4;js++) a2[js] = (f32x4){0.f,0.f,0.f,0.f};
  dft_partial(ldt, os, q, lr, tf, blockIdx.x, a2);
  // NT partial stores: zero L2-reuse data, keep it out of L2
  unsigned* pp = pout + ((size_t)blockIdx.x*64 + b)*2048 + os*256 + q*64 + lr;
  #pragma unroll
  for (int js=0;js<4;js++){
    __builtin_nontemporal_store(pk_bf(a2[js][0], a2[js][1]), pp + js*16);
    __builtin_nontemporal_store(pk_bf(a2[js][2], a2[js][3]), pp + 1024 + js*16);
  }
}

// ---- fused reduce+mix: 256 blocks = (b 64) x (jg 4). Phase1 reduces the
// block's own 512-u32 partial slice (NT loads — single-use data).
// Phase2 mixes with lane-coalesced transposed weights. Output: hi-frags only.
__global__ __launch_bounds__(256) void k_redmix(const unsigned* __restrict__ pb,
    const float* __restrict__ twr, const float* __restrict__ twi,
    unsigned short* __restrict__ mh){
  __shared__ float xs[64*16];   // [c][jloc]
  int jg = blockIdx.x & 3, b = blockIdx.x >> 2;
  int tid = threadIdx.x;
  {
    int pair = tid >> 7, os = (tid >> 5) & 3, q = (tid >> 3) & 3, lr8 = tid & 7;
    size_t base = (size_t)b*2048 + pair*1024 + os*256 + q*64 + jg*16 + lr8;
    float s0l=0.f,s0h=0.f,s1l=0.f,s1h=0.f;
    #pragma unroll 3
    for (int p=0;p<PCH;p++){
      unsigned v0 = __builtin_nontemporal_load(pb + (size_t)p*131072 + base);
      unsigned v1 = __builtin_nontemporal_load(pb + (size_t)p*131072 + base + 8);
      s0l += __uint_as_float(v0<<16); s0h += __uint_as_float(v0 & 0xFFFF0000u);
      s1l += __uint_as_float(v1<<16); s1h += __uint_as_float(v1 & 0xFFFF0000u);
    }
    int c0 = os*16 + q*4 + pair*2;
    xs[(c0  )*16 + lr8]   = s0l;  xs[(c0+1)*16 + lr8]   = s0h;
    xs[(c0  )*16 + lr8+8] = s1l;  xs[(c0+1)*16 + lr8+8] = s1h;
  }
  __syncthreads();
  int o = tid & 63;
  #pragma unroll
  for (int t=0;t<2;t++){
    int mloc = (tid >> 6) + t*4;
    int m = jg*8 + mloc;
    int jl = 2*mloc;
    const float* wr = twr + (size_t)m*4096 + o;
    const float* wi = twi + (size_t)m*4096 + o;
    float ar=0.f, ai=0.f;
    for (int i=0;i<64;i++){
      float xr = xs[i*16 + jl], xi_ = xs[i*16 + jl + 1];
      float wrv = wr[i*64], wiv = wi[i*64];
      ar = fmaf(xr,wrv,ar); ar = fmaf(-xi_,wiv,ar);
      ai = fmaf(xr,wiv,ai); ai = fmaf(xi_,wrv,ai);
    }
    int j2 = 2*m;
    int ks2 = j2 >> 5, rem = j2 & 31, qq = rem >> 3, e = rem & 7;
    int lane = qq*16 + (o & 15), osn = o >> 4;
    size_t a = ((size_t)(((b*2 + ks2)*4 + osn)*64 + lane))*8 + e;
    *(unsigned*)(mh + a) = pk_bf(ar, ai);
  }
}

__device__ inline void conv_pass(const char* xb, int bx, int lane,
    const short8 ch_[2], f32x4 acc[8]){
  #pragma unroll
  for (int ks=0;ks<2;ks++){
    #pragma unroll
    for (int ls=0;ls<8;ls++){
      short8 bh = *(const short8*)(xb + ((size_t)((bx*8 + ls)*2 + ks))*1024 + lane*16);
      acc[ls] = __builtin_amdgcn_mfma_f32_16x16x32_bf16(ch_[ks], bh, acc[ls], 0,0,0);
    }
  }
}
__device__ inline void spec_pass(const unsigned short* __restrict__ tif, int bx, int lane,
    const short8 mh_[2], f32x4 acc[8]){
  #pragma unroll
  for (int ks=0;ks<2;ks++){
    #pragma unroll
    for (int ls=0;ls<8;ls++){
      short8 bt = *(const short8*)(tif + ((size_t)((ks*NLB + bx*8 + ls)*64 + lane))*8);
      acc[ls] = __builtin_amdgcn_mfma_f32_16x16x32_bf16(mh_[ks], bt, acc[ls], 0,0,0);
    }
  }
}

// ---- fused layer: conv (hi) + spectral (hi) MFMA, tiled stores,
//      tr-read LDS transpose (wave-private, no barrier), fused partial DFT
__global__ __launch_bounds__(256) void k_layer(
    const unsigned short* __restrict__ xlc,
    const unsigned short* __restrict__ wfch,
    const unsigned short* __restrict__ wmh,
    const unsigned short* __restrict__ tif, const unsigned short* __restrict__ tf,
    const float* __restrict__ cb,
    unsigned short* __restrict__ xnh, unsigned* __restrict__ pout,
    float* __restrict__ dout, int last){
  __shared__ __align__(16) unsigned short ldt[LDT_BYTES/2];
  int l0 = blockIdx.x * 128; int b = blockIdx.y;
  int tid = threadIdx.x;
  int os = tid >> 6, lane = tid & 63, q = lane >> 4, lr = lane & 15;
  const char* xb = (const char*)xlc + (size_t)b*BST;

  short8 ch_[2], mh_[2];
  #pragma unroll
  for (int ks=0;ks<2;ks++){
    size_t a = ((size_t)((ks*4 + os)*64 + lane))*8;
    ch_[ks] = *(const short8*)(wfch + a);
    size_t am = ((size_t)(((b*2 + ks)*4 + os)*64 + lane))*8;
    mh_[ks] = *(const short8*)(wmh + am);
  }
  f32x4 acc[8];
  #pragma unroll
  for (int ls=0;ls<8;ls++) acc[ls] = (f32x4){0.f,0.f,0.f,0.f};
  if ((blockIdx.x + b) & 1){
    spec_pass(tif, blockIdx.x, lane, mh_, acc);
    conv_pass(xb, blockIdx.x, lane, ch_, acc);
  } else {
    conv_pass(xb, blockIdx.x, lane, ch_, acc);
    spec_pass(tif, blockIdx.x, lane, mh_, acc);
  }
  float bias[4];
  #pragma unroll
  for (int r=0;r<4;r++) bias[r] = cb[os*16 + 4*q + r];

  if (!last){
    char* nb = (char*)xnh + (size_t)b*BST;
    int cks = os >> 1;
    int qp  = (os & 1)*2 + (q >> 1);
    int e0  = (q & 1)*4;
    char* ldb = (char*)ldt + os*4096 + q*8;
    #pragma unroll
    for (int ls=0;ls<8;ls++){
      int lrow = ls*16 + lr; int l = l0 + lrow;
      unsigned h0 = 0, h1 = 0;
      if (l < NFFT){
        h0 = pk_bf(gelu_f(acc[ls][0] + bias[0]), gelu_f(acc[ls][1] + bias[1]));
        h1 = pk_bf(gelu_f(acc[ls][2] + bias[2]), gelu_f(acc[ls][3] + bias[3]));
      }
      int lblk = blockIdx.x*8 + ls;
      *(uint2*)(nb + ((size_t)(lblk*2 + cks))*1024 + (qp*16 + lr)*16 + e0*2) = make_uint2(h0,h1);
      *(uint2*)(ldb + lrow*32) = make_uint2(h0,h1);
    }
    // no barrier: ldt subtile is wave-private (dft_partial waits lgkmcnt)
    f32x4 a2[4];
    #pragma unroll
    for (int js=0;js<4;js++) a2[js] = (f32x4){0.f,0.f,0.f,0.f};
    dft_partial(ldt, os, q, lr, tf, blockIdx.x, a2);
    // NT partial stores: keep zero-reuse partials out of L2 so the x-plane
    // tiles written above stay resident for the next layer's conv reads
    unsigned* pp = pout + ((size_t)blockIdx.x*64 + b)*2048 + os*256 + q*64 + lr;
    #pragma unroll
    for (int js=0;js<4;js++){
      __builtin_nontemporal_store(pk_bf(a2[js][0], a2[js][1]), pp + js*16);
      __builtin_nontemporal_store(pk_bf(a2[js][2], a2[js][3]), pp + 1024 + js*16);
    }
  } else {
    #pragma unroll
    for (int ls=0;ls<8;ls++){
      int l = l0 + ls*16 + lr;
      if (l < LL){
        #pragma unroll
        for (int r=0;r<4;r++){
          int o = os*16 + 4*q + r;
          __builtin_nontemporal_store(acc[ls][r] + bias[r],
                                      &dout[((size_t)(b*64 + o))*LL + l]);
        }
      }
    }
  }
}

extern "C" void kernel_launch(void* const* d_in, const int* in_sizes, int n_in,
                              void* d_out, int out_size, void* d_ws, size_t ws_size,
                              hipStream_t stream) {
  const float* x   = (const float*)d_in[0];
  const float* lw  = (const float*)d_in[1];
  const float* lb  = (const float*)d_in[2];
  const float* cw  = (const float*)d_in[3];
  const float* cb  = (const float*)d_in[4];
  const float* swr = (const float*)d_in[5];
  const float* swi = (const float*)d_in[6];

  char* ws = (char*)d_ws;
  size_t PL = (size_t)NB*BST;                 // 34,603,008 bytes per plane
  unsigned short* x0lc = (unsigned short*)(ws);
  unsigned short* x1lc = (unsigned short*)(ws + PL);
  unsigned short* tf   = (unsigned short*)(ws + 2*PL);
  unsigned short* tif  = (unsigned short*)(ws + 2*PL + 540672);
  unsigned short* wfch = (unsigned short*)(ws + 2*PL + 2*540672);
  unsigned short* wmh  = (unsigned short*)(ws + 2*PL + 2*540672 + 32768);
  float*          twr  = (float*)        (ws + 2*PL + 2*540672 + 32768 + 524288);
  float*          twi  = twr + 524288;        // 2MB each (4L x 32m x 64i x 64o)
  unsigned*       pA   = (unsigned*)(twi + 524288);       // 33 x 512KB bf16-pair chunks
  unsigned*       pB   = pA + (size_t)PCH*131072;

  k_tables<<<6272, 256,0,stream>>>(cw, swr, swi, tf, tif, wfch, twr, twi);
  k_lift2 <<<dim3(LCH,NB),256,0,stream>>>(x, lw, lb, tf, x0lc, pA);

  for (int k=0;k<NRL;k++){
    unsigned short* curlc = (k&1) ? x1lc : x0lc;
    unsigned short* nxtlc = (k&1) ? x0lc : x1lc;
    unsigned* psrc = (k&1) ? pB : pA;
    unsigned* pdst = (k&1) ? pA : pB;
    k_redmix<<<256, 256,0,stream>>>(psrc, twr + (size_t)k*131072, twi + (size_t)k*131072,
                                    wmh);
    k_layer<<<dim3(LCH,NB),256,0,stream>>>(curlc,
        wfch + (size_t)k*4096, wmh, tif, tf,
        cb + (size_t)k*64, nxtlc, pdst, (float*)d_out, (k==NRL-1) ? 1 : 0);
  }
}

// Round 23
// 158.779 us; speedup vs baseline: 1.0549x; 1.0549x over previous
//
#include <hip/hip_runtime.h>
#include <hip/hip_bf16.h>
#include <math.h>

#define NRL 4
#define LL 4096
#define NFFT 4104
#define LP 4224
#define NB 64
#define WD 64
#define BST (LP*WD*2)        // 540672 bytes per batch plane (tiled layout)
#define LCH 33               // l-chunks of 128
#define PCH 33               // partial chunks
#define NLB 264              // l-tiles of 16 (LP/16)
#define PI2 6.28318530717958647692f

typedef __attribute__((ext_vector_type(8))) short short8;
typedef __attribute__((ext_vector_type(4))) short short4v;
typedef __attribute__((ext_vector_type(4))) float f32x4;

__device__ inline unsigned short f2bf(float f){
  unsigned int u = __float_as_uint(f);
  return (unsigned short)((u + 0x7FFFu + ((u>>16)&1u)) >> 16);
}
__device__ inline unsigned pk_bf(float lo, float hi){
  unsigned r;
  asm("v_cvt_pk_bf16_f32 %0, %1, %2" : "=v"(r) : "v"(lo), "v"(hi));
  return r;
}
// tanh-form gelu: |err vs erf-gelu| <= ~5e-4
__device__ inline float gelu_f(float v){
  float v2 = v*v;
  float z = v * fmaf(0.07135481627f, v2, 1.5957691216f);
  float e = __expf(-z);
  return v * __builtin_amdgcn_rcpf(1.0f + e);
}

// x-plane tiled layout: per b, [lblk 264][cks 2][lane 64][e 8] bf16 (1KB tiles)

// ---- prologue: tf (1056) | tif tiled (1056) | conv-w frags hi (64) |
//      transposed spectral weights twr (2048) | twi (2048)
__global__ void k_tables(const float* __restrict__ cw,
                         const float* __restrict__ swr, const float* __restrict__ swi,
                         unsigned short* __restrict__ tf,
                         unsigned short* __restrict__ tif,
                         unsigned short* __restrict__ whi,
                         float* __restrict__ twr, float* __restrict__ twi){
  int bid = blockIdx.x;
  if (bid < 1056){
    int idx = bid*256 + threadIdx.x;          // 270336
    int e = idx & 7; int t = idx >> 3;
    int lane = t & 63; int t2 = t >> 6;
    int js = t2 & 3; int ks = t2 >> 2;
    int l = ks*32 + 8*(lane>>4) + e;
    int j = js*16 + (lane & 15);
    int m = j >> 1;
    float v = 0.f;
    if (l < NFFT){
      int r = (m*l) % NFFT;
      float ang = PI2 * ((float)r / (float)NFFT);
      v = (j & 1) ? -__sinf(ang) : __cosf(ang);
    }
    tf[idx] = f2bf(v);
  } else if (bid < 2112){
    int idx = (bid-1056)*256 + threadIdx.x;   // 270336
    int e = idx & 7; int t = idx >> 3;
    int lane = t & 63; int u = t >> 6;
    int lblk = u % NLB; int ks = u / NLB;
    int j2 = ks*32 + 8*(lane>>4) + e;
    int l = lblk*16 + (lane & 15);
    int m = j2 >> 1;
    float v = 0.f;
    if (l < NFFT){
      int r = (m*l) % NFFT;
      float ang = PI2 * ((float)r / (float)NFFT);
      float inv = 1.0f/(float)NFFT;
      v = (j2 & 1) ? (-2.f*inv*__sinf(ang)) : ((m==0?inv:2.f*inv)*__cosf(ang));
    }
    tif[idx] = f2bf(v);
  } else if (bid < 2176){
    int idx = (bid-2112)*256 + threadIdx.x;   // 16384
    int e = idx & 7; int lane = (idx>>3)&63; int os = (idx>>9)&3;
    int ks2 = (idx>>11)&1; int ly = idx>>12;
    int k = ks2*32 + 8*(lane>>4) + e;
    int o = os*16 + (lane&15);
    whi[idx] = f2bf(cw[((size_t)(ly*64 + o))*64 + k]);
  } else if (bid < 4224){
    int idx = (bid-2176)*256 + threadIdx.x;   // 524288: [ly][m][i][o]
    int o = idx & 63, i = (idx>>6)&63, m = (idx>>12)&31, ly = idx>>17;
    twr[idx] = swr[(((size_t)(ly*64 + i)*64 + o))*32 + m];
  } else {
    int idx = (bid-4224)*256 + threadIdx.x;   // 524288
    int o = idx & 63, i = (idx>>6)&63, m = (idx>>12)&31, ly = idx>>17;
    twi[idx] = swi[(((size_t)(ly*64 + i)*64 + o))*32 + m];
  }
}

// LDS transpose tile: ldt[os 4][l 128][c 16] u16 (row = 32B).
// Wave-private subtile: no __syncthreads needed (lgkmcnt wait only).
#define LDT_BYTES 16384

__device__ inline void dft_partial(const unsigned short* ldt_base, int os, int q, int lr,
                                   const unsigned short* __restrict__ tf, int chunk,
                                   f32x4 a2[4]){
  unsigned ab = (unsigned)(size_t)ldt_base + (unsigned)(os*4096 + q*256 + lr*2);
  short4v t0,t1,t2,t3,t4,t5,t6,t7;
  asm volatile("s_waitcnt lgkmcnt(0)" ::: "memory");   // own ds_writes complete
  asm volatile("ds_read_b64_tr_b16 %0, %1 offset:0"    : "=v"(t0) : "v"(ab) : "memory");
  asm volatile("ds_read_b64_tr_b16 %0, %1 offset:128"  : "=v"(t1) : "v"(ab) : "memory");
  asm volatile("ds_read_b64_tr_b16 %0, %1 offset:1024" : "=v"(t2) : "v"(ab) : "memory");
  asm volatile("ds_read_b64_tr_b16 %0, %1 offset:1152" : "=v"(t3) : "v"(ab) : "memory");
  asm volatile("ds_read_b64_tr_b16 %0, %1 offset:2048" : "=v"(t4) : "v"(ab) : "memory");
  asm volatile("ds_read_b64_tr_b16 %0, %1 offset:2176" : "=v"(t5) : "v"(ab) : "memory");
  asm volatile("ds_read_b64_tr_b16 %0, %1 offset:3072" : "=v"(t6) : "v"(ab) : "memory");
  asm volatile("ds_read_b64_tr_b16 %0, %1 offset:3200" : "=v"(t7) : "v"(ab) : "memory");
  asm volatile("s_waitcnt lgkmcnt(0)" ::: "memory");
  __builtin_amdgcn_sched_barrier(0);
  short8 av0 = __builtin_shufflevector(t0, t1, 0,1,2,3,4,5,6,7);
  short8 av1 = __builtin_shufflevector(t2, t3, 0,1,2,3,4,5,6,7);
  short8 av2 = __builtin_shufflevector(t4, t5, 0,1,2,3,4,5,6,7);
  short8 av3 = __builtin_shufflevector(t6, t7, 0,1,2,3,4,5,6,7);
  int lane = q*16 + lr;
  #pragma unroll
  for (int js=0;js<4;js++){
    short8 bv0 = *(const short8*)(tf + ((size_t)(((chunk*4 + 0)*4 + js)*64 + lane))*8);
    a2[js] = __builtin_amdgcn_mfma_f32_16x16x32_bf16(av0, bv0, a2[js], 0,0,0);
    short8 bv1 = *(const short8*)(tf + ((size_t)(((chunk*4 + 1)*4 + js)*64 + lane))*8);
    a2[js] = __builtin_amdgcn_mfma_f32_16x16x32_bf16(av1, bv1, a2[js], 0,0,0);
    short8 bv2 = *(const short8*)(tf + ((size_t)(((chunk*4 + 2)*4 + js)*64 + lane))*8);
    a2[js] = __builtin_amdgcn_mfma_f32_16x16x32_bf16(av2, bv2, a2[js], 0,0,0);
    short8 bv3 = *(const short8*)(tf + ((size_t)(((chunk*4 + 3)*4 + js)*64 + lane))*8);
    a2[js] = __builtin_amdgcn_mfma_f32_16x16x32_bf16(av3, bv3, a2[js], 0,0,0);
  }
}

// ---- fused lift: lifted x -> tiled plane + LDS transpose -> partial DFT chunk
__global__ __launch_bounds__(256) void k_lift2(const float* __restrict__ x,
    const float* __restrict__ lw, const float* __restrict__ lb,
    const unsigned short* __restrict__ tf,
    unsigned short* __restrict__ xh, unsigned* __restrict__ pout){
  __shared__ __align__(16) unsigned short ldt[LDT_BYTES/2];
  __shared__ float xs[128];
  int l0 = blockIdx.x*128; int b = blockIdx.y;
  int tid = threadIdx.x;
  int os = tid >> 6, lane = tid & 63, q = lane >> 4, lr = lane & 15;
  if (tid < 32){
    float4 v = make_float4(0.f,0.f,0.f,0.f);
    int l = l0 + tid*4;
    if (l < LL) v = *(const float4*)(x + (size_t)b*LL + l);
    *(float4*)(xs + tid*4) = v;
  }
  __syncthreads();        // xs is cross-wave shared: keep this barrier
  float w0[4], w1[4], bb[4];
  #pragma unroll
  for (int r=0;r<4;r++){
    int c = os*16 + 4*q + r;
    w0[r] = lw[2*c]; w1[r] = lw[2*c+1]; bb[r] = lb[c];
  }
  char* nb = (char*)xh + (size_t)b*BST;
  int cks = os >> 1;
  int qp  = (os & 1)*2 + (q >> 1);
  int e0  = (q & 1)*4;
  char* ldb = (char*)ldt + os*4096 + q*8;
  #pragma unroll
  for (int ls=0;ls<8;ls++){
    int lrow = ls*16 + lr; int l = l0 + lrow;
    float g = (float)l * (1.0f/4095.0f);
    float v0 = (l < LL) ? fmaf(w0[0], xs[lrow], fmaf(w1[0], g, bb[0])) : 0.f;
    float v1 = (l < LL) ? fmaf(w0[1], xs[lrow], fmaf(w1[1], g, bb[1])) : 0.f;
    float v2 = (l < LL) ? fmaf(w0[2], xs[lrow], fmaf(w1[2], g, bb[2])) : 0.f;
    float v3 = (l < LL) ? fmaf(w0[3], xs[lrow], fmaf(w1[3], g, bb[3])) : 0.f;
    unsigned h0 = pk_bf(v0, v1), h1 = pk_bf(v2, v3);
    int lblk = blockIdx.x*8 + ls;
    *(uint2*)(nb + ((size_t)(lblk*2 + cks))*1024 + (qp*16 + lr)*16 + e0*2) = make_uint2(h0,h1);
    *(uint2*)(ldb + lrow*32) = make_uint2(h0,h1);
  }
  // no barrier: ldt subtile is wave-private (dft_partial waits lgkmcnt)
  f32x4 a2[4];
  #pragma unroll
  for (int js=0;js<4;js++) a2[js] = (f32x4){0.f,0.f,0.f,0.f};
  dft_partial(ldt, os, q, lr, tf, blockIdx.x, a2);
  unsigned* pp = pout + ((size_t)blockIdx.x*64 + b)*2048 + os*256 + q*64 + lr;
  #pragma unroll
  for (int js=0;js<4;js++){
    pp[js*16]        = pk_bf(a2[js][0], a2[js][1]);
    pp[1024 + js*16] = pk_bf(a2[js][2], a2[js][3]);
  }
}

// ---- fused reduce+mix: 256 blocks = (b 64) x (jg 4). Phase1 reduces the
// block's own 512-u32 partial slice. Phase2 mixes with lane-coalesced
// transposed weights. Output: hi-frags only.
__global__ __launch_bounds__(256) void k_redmix(const unsigned* __restrict__ pb,
    const float* __restrict__ twr, const float* __restrict__ twi,
    unsigned short* __restrict__ mh){
  __shared__ float xs[64*16];   // [c][jloc]
  int jg = blockIdx.x & 3, b = blockIdx.x >> 2;
  int tid = threadIdx.x;
  {
    int pair = tid >> 7, os = (tid >> 5) & 3, q = (tid >> 3) & 3, lr8 = tid & 7;
    size_t base = (size_t)b*2048 + pair*1024 + os*256 + q*64 + jg*16 + lr8;
    float s0l=0.f,s0h=0.f,s1l=0.f,s1h=0.f;
    #pragma unroll 3
    for (int p=0;p<PCH;p++){
      unsigned v0 = pb[(size_t)p*131072 + base];
      unsigned v1 = pb[(size_t)p*131072 + base + 8];
      s0l += __uint_as_float(v0<<16); s0h += __uint_as_float(v0 & 0xFFFF0000u);
      s1l += __uint_as_float(v1<<16); s1h += __uint_as_float(v1 & 0xFFFF0000u);
    }
    int c0 = os*16 + q*4 + pair*2;
    xs[(c0  )*16 + lr8]   = s0l;  xs[(c0+1)*16 + lr8]   = s0h;
    xs[(c0  )*16 + lr8+8] = s1l;  xs[(c0+1)*16 + lr8+8] = s1h;
  }
  __syncthreads();
  int o = tid & 63;
  #pragma unroll
  for (int t=0;t<2;t++){
    int mloc = (tid >> 6) + t*4;
    int m = jg*8 + mloc;
    int jl = 2*mloc;
    const float* wr = twr + (size_t)m*4096 + o;
    const float* wi = twi + (size_t)m*4096 + o;
    float ar=0.f, ai=0.f;
    for (int i=0;i<64;i++){
      float xr = xs[i*16 + jl], xi_ = xs[i*16 + jl + 1];
      float wrv = wr[i*64], wiv = wi[i*64];
      ar = fmaf(xr,wrv,ar); ar = fmaf(-xi_,wiv,ar);
      ai = fmaf(xr,wiv,ai); ai = fmaf(xi_,wrv,ai);
    }
    int j2 = 2*m;
    int ks2 = j2 >> 5, rem = j2 & 31, qq = rem >> 3, e = rem & 7;
    int lane = qq*16 + (o & 15), osn = o >> 4;
    size_t a = ((size_t)(((b*2 + ks2)*4 + osn)*64 + lane))*8 + e;
    *(unsigned*)(mh + a) = pk_bf(ar, ai);
  }
}

__device__ inline void conv_pass(const char* xb, int bx, int lane,
    const short8 ch_[2], f32x4 acc[8]){
  #pragma unroll
  for (int ks=0;ks<2;ks++){
    #pragma unroll
    for (int ls=0;ls<8;ls++){
      short8 bh = *(const short8*)(xb + ((size_t)((bx*8 + ls)*2 + ks))*1024 + lane*16);
      acc[ls] = __builtin_amdgcn_mfma_f32_16x16x32_bf16(ch_[ks], bh, acc[ls], 0,0,0);
    }
  }
}
__device__ inline void spec_pass(const unsigned short* __restrict__ tif, int bx, int lane,
    const short8 mh_[2], f32x4 acc[8]){
  #pragma unroll
  for (int ks=0;ks<2;ks++){
    #pragma unroll
    for (int ls=0;ls<8;ls++){
      short8 bt = *(const short8*)(tif + ((size_t)((ks*NLB + bx*8 + ls)*64 + lane))*8);
      acc[ls] = __builtin_amdgcn_mfma_f32_16x16x32_bf16(mh_[ks], bt, acc[ls], 0,0,0);
    }
  }
}

// ---- fused layer: conv (hi) + spectral (hi) MFMA, tiled stores,
//      tr-read LDS transpose (wave-private, no barrier), fused partial DFT
__global__ __launch_bounds__(256) void k_layer(
    const unsigned short* __restrict__ xlc,
    const unsigned short* __restrict__ wfch,
    const unsigned short* __restrict__ wmh,
    const unsigned short* __restrict__ tif, const unsigned short* __restrict__ tf,
    const float* __restrict__ cb,
    unsigned short* __restrict__ xnh, unsigned* __restrict__ pout,
    float* __restrict__ dout, int last){
  __shared__ __align__(16) unsigned short ldt[LDT_BYTES/2];
  int l0 = blockIdx.x * 128; int b = blockIdx.y;
  int tid = threadIdx.x;
  int os = tid >> 6, lane = tid & 63, q = lane >> 4, lr = lane & 15;
  const char* xb = (const char*)xlc + (size_t)b*BST;

  short8 ch_[2], mh_[2];
  #pragma unroll
  for (int ks=0;ks<2;ks++){
    size_t a = ((size_t)((ks*4 + os)*64 + lane))*8;
    ch_[ks] = *(const short8*)(wfch + a);
    size_t am = ((size_t)(((b*2 + ks)*4 + os)*64 + lane))*8;
    mh_[ks] = *(const short8*)(wmh + am);
  }
  f32x4 acc[8];
  #pragma unroll
  for (int ls=0;ls<8;ls++) acc[ls] = (f32x4){0.f,0.f,0.f,0.f};
  if ((blockIdx.x + b) & 1){
    spec_pass(tif, blockIdx.x, lane, mh_, acc);
    conv_pass(xb, blockIdx.x, lane, ch_, acc);
  } else {
    conv_pass(xb, blockIdx.x, lane, ch_, acc);
    spec_pass(tif, blockIdx.x, lane, mh_, acc);
  }
  float bias[4];
  #pragma unroll
  for (int r=0;r<4;r++) bias[r] = cb[os*16 + 4*q + r];

  if (!last){
    char* nb = (char*)xnh + (size_t)b*BST;
    int cks = os >> 1;
    int qp  = (os & 1)*2 + (q >> 1);
    int e0  = (q & 1)*4;
    char* ldb = (char*)ldt + os*4096 + q*8;
    #pragma unroll
    for (int ls=0;ls<8;ls++){
      int lrow = ls*16 + lr; int l = l0 + lrow;
      unsigned h0 = 0, h1 = 0;
      if (l < NFFT){
        h0 = pk_bf(gelu_f(acc[ls][0] + bias[0]), gelu_f(acc[ls][1] + bias[1]));
        h1 = pk_bf(gelu_f(acc[ls][2] + bias[2]), gelu_f(acc[ls][3] + bias[3]));
      }
      int lblk = blockIdx.x*8 + ls;
      *(uint2*)(nb + ((size_t)(lblk*2 + cks))*1024 + (qp*16 + lr)*16 + e0*2) = make_uint2(h0,h1);
      *(uint2*)(ldb + lrow*32) = make_uint2(h0,h1);
    }
    // no barrier: ldt subtile is wave-private (dft_partial waits lgkmcnt)
    f32x4 a2[4];
    #pragma unroll
    for (int js=0;js<4;js++) a2[js] = (f32x4){0.f,0.f,0.f,0.f};
    dft_partial(ldt, os, q, lr, tf, blockIdx.x, a2);
    unsigned* pp = pout + ((size_t)blockIdx.x*64 + b)*2048 + os*256 + q*64 + lr;
    #pragma unroll
    for (int js=0;js<4;js++){
      pp[js*16]        = pk_bf(a2[js][0], a2[js][1]);
      pp[1024 + js*16] = pk_bf(a2[js][2], a2[js][3]);
    }
  } else {
    #pragma unroll
    for (int ls=0;ls<8;ls++){
      int l = l0 + ls*16 + lr;
      if (l < LL){
        #pragma unroll
        for (int r=0;r<4;r++){
          int o = os*16 + 4*q + r;
          __builtin_nontemporal_store(acc[ls][r] + bias[r],
                                      &dout[((size_t)(b*64 + o))*LL + l]);
        }
      }
    }
  }
}

extern "C" void kernel_launch(void* const* d_in, const int* in_sizes, int n_in,
                              void* d_out, int out_size, void* d_ws, size_t ws_size,
                              hipStream_t stream) {
  const float* x   = (const float*)d_in[0];
  const float* lw  = (const float*)d_in[1];
  const float* lb  = (const float*)d_in[2];
  const float* cw  = (const float*)d_in[3];
  const float* cb  = (const float*)d_in[4];
  const float* swr = (const float*)d_in[5];
  const float* swi = (const float*)d_in[6];

  char* ws = (char*)d_ws;
  size_t PL = (size_t)NB*BST;                 // 34,603,008 bytes per plane
  unsigned short* x0lc = (unsigned short*)(ws);
  unsigned short* x1lc = (unsigned short*)(ws + PL);
  unsigned short* tf   = (unsigned short*)(ws + 2*PL);
  unsigned short* tif  = (unsigned short*)(ws + 2*PL + 540672);
  unsigned short* wfch = (unsigned short*)(ws + 2*PL + 2*540672);
  unsigned short* wmh  = (unsigned short*)(ws + 2*PL + 2*540672 + 32768);
  float*          twr  = (float*)        (ws + 2*PL + 2*540672 + 32768 + 524288);
  float*          twi  = twr + 524288;        // 2MB each (4L x 32m x 64i x 64o)
  unsigned*       pA   = (unsigned*)(twi + 524288);       // 33 x 512KB bf16-pair chunks
  unsigned*       pB   = pA + (size_t)PCH*131072;

  k_tables<<<6272, 256,0,stream>>>(cw, swr, swi, tf, tif, wfch, twr, twi);
  k_lift2 <<<dim3(LCH,NB),256,0,stream>>>(x, lw, lb, tf, x0lc, pA);

  for (int k=0;k<NRL;k++){
    unsigned short* curlc = (k&1) ? x1lc : x0lc;
    unsigned short* nxtlc = (k&1) ? x0lc : x1lc;
    unsigned* psrc = (k&1) ? pB : pA;
    unsigned* pdst = (k&1) ? pA : pB;
    k_redmix<<<256, 256,0,stream>>>(psrc, twr + (size_t)k*131072, twi + (size_t)k*131072,
                                    wmh);
    k_layer<<<dim3(LCH,NB),256,0,stream>>>(curlc,
        wfch + (size_t)k*4096, wmh, tif, tf,
        cb + (size_t)k*64, nxtlc, pdst, (float*)d_out, (k==NRL-1) ? 1 : 0);
  }
}